// Round 13
// baseline (427.375 us; speedup 1.0000x reference)
//
#include <hip/hip_runtime.h>

// ---------------------------------------------------------------------------
// 2-layer GAT (PyG GATConv), MI355X.
// R13: BARRIER-FREE MFMA GEMM. A and B fragments both gathered directly from
//      global (fragment wants A[row+fr][k+fq*8..+7] = 16 rows x 64B
//      contiguous = perfect 16-line gather; panels are L2-resident). No LDS,
//      no __syncthreads, no vmcnt(0) drain -> compiler pipelines the K-loop.
//      R12's LDS staging bought no reuse L2 doesn't give (A read 2x/block,
//      128KB) and cost 2 barriers per 32-k on an 8-iteration loop.
//      aggr / CSR / prep unchanged from R12.
// ---------------------------------------------------------------------------

typedef __attribute__((ext_vector_type(8))) short short8;
typedef __attribute__((ext_vector_type(4))) float f32x4;

static __device__ __forceinline__ ushort f2bf(float f) {  // RNE
  uint u = __float_as_uint(f);
  return (ushort)((u + 0x7FFFu + ((u >> 16) & 1u)) >> 16);
}
static __device__ __forceinline__ float bf2f(ushort s) {
  return __uint_as_float(((uint)s) << 16);
}
static __device__ __forceinline__ void split8(const float4& a, const float4& b,
                                              short8& fh, short8& fl) {
  ushort h0 = f2bf(a.x), h1 = f2bf(a.y), h2 = f2bf(a.z), h3 = f2bf(a.w);
  ushort h4 = f2bf(b.x), h5 = f2bf(b.y), h6 = f2bf(b.z), h7 = f2bf(b.w);
  fh = short8{(short)h0, (short)h1, (short)h2, (short)h3,
              (short)h4, (short)h5, (short)h6, (short)h7};
  fl = short8{(short)f2bf(a.x - bf2f(h0)), (short)f2bf(a.y - bf2f(h1)),
              (short)f2bf(a.z - bf2f(h2)), (short)f2bf(a.w - bf2f(h3)),
              (short)f2bf(b.x - bf2f(h4)), (short)f2bf(b.y - bf2f(h5)),
              (short)f2bf(b.z - bf2f(h6)), (short)f2bf(b.w - bf2f(h7))};
}

// ----------------------------- CSR build -----------------------------------
__global__ __launch_bounds__(256)
void k_hist(const int* __restrict__ dstv, int* __restrict__ cnt, int E) {
  int i = blockIdx.x * 256 + threadIdx.x;
  if (i < E) atomicAdd(&cnt[dstv[i]], 1);
}

// Single-pass exclusive scan with decoupled lookback (grid <= 256 blocks).
__global__ __launch_bounds__(256)
void k_scan(const int* __restrict__ cnt, int* __restrict__ rowptr,
            int* __restrict__ cursor, int* __restrict__ bsum,
            int* __restrict__ bflag, int N, int E) {
  __shared__ int sm[256];
  __shared__ int s_prev;
  const int b = blockIdx.x, tid = threadIdx.x;
  const int gid = b * 256 + tid;
  int v = (gid < N) ? cnt[gid] : 0;
  sm[tid] = v;
  __syncthreads();
  for (int off = 1; off < 256; off <<= 1) {
    int t = (tid >= off) ? sm[tid - off] : 0;
    __syncthreads();
    sm[tid] += t;
    __syncthreads();
  }
  if (tid == 255) {
    atomicExch(&bsum[b], sm[255]);
    __threadfence();
    atomicExch(&bflag[b], 1);
  }
  if (tid == 0) s_prev = 0;
  __syncthreads();
  if (tid < b) {
    while (atomicAdd(&bflag[tid], 0) == 0) {}
    atomicAdd(&s_prev, atomicAdd(&bsum[tid], 0));
  }
  __syncthreads();
  if (gid < N) {
    int rp = s_prev + sm[tid] - v;
    rowptr[gid] = rp;
    cursor[gid] = rp;
  }
  if (gid == 0) rowptr[N] = E;
}

__global__ __launch_bounds__(256)
void k_scatter(const int* __restrict__ srcv, const int* __restrict__ dstv,
               int* __restrict__ cursor, int* __restrict__ col, int E) {
  int i = blockIdx.x * 256 + threadIdx.x;
  if (i < E) {
    int p = atomicAdd(&cursor[dstv[i]], 1);
    col[p] = srcv[i];
  }
}

// --------------------- weight prep (both layers, one launch) ---------------
__global__ __launch_bounds__(256)
void k_prep_w(const float* __restrict__ W1, const float* __restrict__ W2,
              ushort* __restrict__ w1th, ushort* __restrict__ w1tl,
              ushort* __restrict__ w2th, ushort* __restrict__ w2tl) {
  int bid = blockIdx.x;
  if (bid < 128) {  // W1 [128][256] -> [256][128] split
    int gid = bid * 256 + threadIdx.x;
    int c = gid & 255, k = gid >> 8;
    float w = W1[(size_t)k * 256 + c];
    ushort h = f2bf(w);
    w1th[(size_t)c * 128 + k] = h;
    w1tl[(size_t)c * 128 + k] = f2bf(w - bf2f(h));
  } else {          // W2 [256][256] -> [256][256] split
    int gid = (bid - 128) * 256 + threadIdx.x;
    int c = gid & 255, k = gid >> 8;
    float w = W2[(size_t)k * 256 + c];
    ushort h = f2bf(w);
    w2th[(size_t)c * 256 + k] = h;
    w2tl[(size_t)c * 256 + k] = f2bf(w - bf2f(h));
  }
}

// ----------------------------- MFMA GEMM -----------------------------------
// C[N,256] = (Ah+Al)[N,K] @ (Bh+Bl)[K,256], Bt stored [256][K].
// SPLIT=1: A is fp32 (x), converted to bf16 h/l in registers per fragment.
// SPLIT=0: A pre-split bf16 (hb_h, hb_l).
// NO LDS, NO barriers: A and B fragments gathered straight from global
// (16 rows x 64B contiguous per fragment load set; panels L2-resident).
// XCD-aligned 1-D swizzle (R11): col-halves of a row block differ by 8
// block ids -> same XCD -> shared A tile hits local L2.
template <int SPLIT>
__global__ __launch_bounds__(256)
void k_gemm_mfma(const void* __restrict__ Aany, const ushort* __restrict__ Al_,
                 const ushort* __restrict__ Bth, const ushort* __restrict__ Btl,
                 ushort* __restrict__ hout, int Nrows, int K,
                 const float* __restrict__ att_s, const float* __restrict__ att_d,
                 float* __restrict__ a_s, float* __restrict__ a_d) {
  const int nrb = (Nrows + 127) >> 7;
  const int bid = blockIdx.x;
  const int rb = (bid >> 4) * 8 + (bid & 7);
  const int ch = (bid >> 3) & 1;
  if (rb >= nrb) return;
  const int row0 = rb * 128;
  const int col0 = ch * 128;

  const int lane = threadIdx.x & 63;
  const int w = threadIdx.x >> 6;
  const int wr = (w >> 1) * 64;
  const int wc = (w & 1) * 64;
  const int fr = lane & 15;
  const int fq = lane >> 4;

  const float*  Af = (const float*)Aany;    // SPLIT=1
  const ushort* Ah = (const ushort*)Aany;   // SPLIT=0

  // clamped fragment row per r (values past Nrows unused at store)
  int grr[4];
#pragma unroll
  for (int r = 0; r < 4; r++) {
    int g = row0 + wr + r * 16 + fr;
    grr[r] = (g < Nrows) ? g : (Nrows - 1);
  }
  // B fragment base: column col0+wc+c*16+fr, k offset fq*8
  const ushort* bb_h = Bth + (size_t)(col0 + wc + fr) * K + fq * 8;
  const ushort* bb_l = Btl + (size_t)(col0 + wc + fr) * K + fq * 8;

  f32x4 acc[4][4] = {};

#pragma unroll 2
  for (int k0 = 0; k0 < K; k0 += 32) {
    short8 fa_h[4], fa_l[4], fb_h[4], fb_l[4];
#pragma unroll
    for (int r = 0; r < 4; r++) {
      if (SPLIT) {
        const float* ap = Af + (size_t)grr[r] * K + k0 + fq * 8;
        float4 a0 = *(const float4*)(ap);
        float4 a1 = *(const float4*)(ap + 4);
        split8(a0, a1, fa_h[r], fa_l[r]);
      } else {
        fa_h[r] = *(const short8*)(Ah + (size_t)grr[r] * K + k0 + fq * 8);
        fa_l[r] = *(const short8*)(Al_ + (size_t)grr[r] * K + k0 + fq * 8);
      }
    }
#pragma unroll
    for (int c = 0; c < 4; c++) {
      fb_h[c] = *(const short8*)(bb_h + (size_t)c * 16 * K + k0);
      fb_l[c] = *(const short8*)(bb_l + (size_t)c * 16 * K + k0);
    }
#pragma unroll
    for (int r = 0; r < 4; r++)
#pragma unroll
      for (int c = 0; c < 4; c++) {
        acc[r][c] = __builtin_amdgcn_mfma_f32_16x16x32_bf16(fa_h[r], fb_h[c], acc[r][c], 0, 0, 0);
        acc[r][c] = __builtin_amdgcn_mfma_f32_16x16x32_bf16(fa_l[r], fb_h[c], acc[r][c], 0, 0, 0);
        acc[r][c] = __builtin_amdgcn_mfma_f32_16x16x32_bf16(fa_h[r], fb_l[c], acc[r][c], 0, 0, 0);
      }
  }

  // ---- C write (bf16, direct — L2 absorbs the 2B scatter, R10 evidence)
#pragma unroll
  for (int r = 0; r < 4; r++)
#pragma unroll
    for (int c = 0; c < 4; c++) {
      int colg = col0 + wc + c * 16 + fr;
#pragma unroll
      for (int reg = 0; reg < 4; reg++) {
        int gr = row0 + wr + r * 16 + fq * 4 + reg;
        if (gr < Nrows) hout[(size_t)gr * 256 + colg] = f2bf(acc[r][c][reg]);
      }
    }

  // ---- attention scores: wave's 64 cols = one head (wc 64-aligned)
  const int head = (col0 + wc) >> 6;
  float asv[4], adv[4];
#pragma unroll
  for (int c = 0; c < 4; c++) {
    asv[c] = att_s[col0 + wc + c * 16 + fr];
    adv[c] = att_d[col0 + wc + c * 16 + fr];
  }
#pragma unroll
  for (int r = 0; r < 4; r++)
#pragma unroll
    for (int reg = 0; reg < 4; reg++) {
      float ps = 0.f, pd = 0.f;
#pragma unroll
      for (int c = 0; c < 4; c++) {
        ps += acc[r][c][reg] * asv[c];
        pd += acc[r][c][reg] * adv[c];
      }
      ps += __shfl_xor(ps, 1); pd += __shfl_xor(pd, 1);
      ps += __shfl_xor(ps, 2); pd += __shfl_xor(pd, 2);
      ps += __shfl_xor(ps, 4); pd += __shfl_xor(pd, 4);
      ps += __shfl_xor(ps, 8); pd += __shfl_xor(pd, 8);
      if (fr == 0) {
        int gr = row0 + wr + r * 16 + fq * 4 + reg;
        if (gr < Nrows) {
          a_s[(size_t)gr * 4 + head] = ps;
          a_d[(size_t)gr * 4 + head] = pd;
        }
      }
    }
}

// ----------------------------- aggregation ---------------------------------
// ONE wave per node; lane owns channels [4*lane, 4*lane+3] (ushort4 gather),
// head = lane>>4. Chunk of 64 edges: lane gathers a_s[col] float4, computes
// all-head weights inline, stages (src, w[4]) in LDS. Denominator free.
// LAYER 1: relu(acc/den + bias) -> split bf16 (out_h, out_l).
// LAYER 2: fused finale — head-mean + bias + relu + softmax(64) -> outp.
template <int LAYER>
__global__ __launch_bounds__(256)
void k_aggr(const ushort* __restrict__ hsrc, const int* __restrict__ rowptr,
            const int* __restrict__ col, const float* __restrict__ a_s,
            const float* __restrict__ a_d, const float* __restrict__ bias,
            ushort* __restrict__ out_h, ushort* __restrict__ out_l,
            float* __restrict__ outp, int N) {
  __shared__ int   s_sh[4][64];
  __shared__ float w_sh[4][256];
  const int wv = threadIdx.x >> 6;
  const int lane = threadIdx.x & 63;
  const int node = blockIdx.x * 4 + wv;
  if (node >= N) return;
  const int hd = lane >> 4;
  const int beg = rowptr[node], end = rowptr[node + 1];
  const float4 adst = *(const float4*)(a_d + (size_t)node * 4);

  float4 acc = make_float4(0.f, 0.f, 0.f, 0.f);
  float wsum = 0.f;
  const char* hbase = (const char*)(hsrc + lane * 4);

  for (int c0 = beg; c0 < end; c0 += 64) {
    int nc = min(64, end - c0);
    int s = 0;
    float4 w4 = make_float4(0.f, 0.f, 0.f, 0.f);
    if (lane < nc) {
      s = col[c0 + lane];
      float4 a = *(const float4*)(a_s + (size_t)s * 4);
      float e0 = a.x + adst.x; e0 = e0 > 0.f ? e0 : 0.2f * e0;
      float e1 = a.y + adst.y; e1 = e1 > 0.f ? e1 : 0.2f * e1;
      float e2 = a.z + adst.z; e2 = e2 > 0.f ? e2 : 0.2f * e2;
      float e3 = a.w + adst.w; e3 = e3 > 0.f ? e3 : 0.2f * e3;
      w4 = make_float4(__expf(e0), __expf(e1), __expf(e2), __expf(e3));
    }
    s_sh[wv][lane] = s;
    *(float4*)(&w_sh[wv][lane * 4]) = w4;
    asm volatile("s_waitcnt lgkmcnt(0)" ::: "memory");

    const float* wrow = &w_sh[wv][hd];
    const int*   srow = &s_sh[wv][0];
    int j = 0;
    for (; j + 4 <= nc; j += 4) {
      int sj0 = srow[j], sj1 = srow[j + 1], sj2 = srow[j + 2], sj3 = srow[j + 3];
      float w0 = wrow[4 * j],      w1 = wrow[4 * j + 4];
      float w2 = wrow[4 * j + 8],  w3 = wrow[4 * j + 12];
      ushort4 u0 = *(const ushort4*)(hbase + ((size_t)((uint)sj0 << 9)));
      ushort4 u1 = *(const ushort4*)(hbase + ((size_t)((uint)sj1 << 9)));
      ushort4 u2 = *(const ushort4*)(hbase + ((size_t)((uint)sj2 << 9)));
      ushort4 u3 = *(const ushort4*)(hbase + ((size_t)((uint)sj3 << 9)));
      wsum += w0 + w1 + w2 + w3;
      acc.x += w0 * bf2f(u0.x); acc.y += w0 * bf2f(u0.y);
      acc.z += w0 * bf2f(u0.z); acc.w += w0 * bf2f(u0.w);
      acc.x += w1 * bf2f(u1.x); acc.y += w1 * bf2f(u1.y);
      acc.z += w1 * bf2f(u1.z); acc.w += w1 * bf2f(u1.w);
      acc.x += w2 * bf2f(u2.x); acc.y += w2 * bf2f(u2.y);
      acc.z += w2 * bf2f(u2.z); acc.w += w2 * bf2f(u2.w);
      acc.x += w3 * bf2f(u3.x); acc.y += w3 * bf2f(u3.y);
      acc.z += w3 * bf2f(u3.z); acc.w += w3 * bf2f(u3.w);
    }
    for (; j < nc; j++) {
      int sj = srow[j];
      float ww = wrow[4 * j];
      ushort4 u = *(const ushort4*)(hbase + ((size_t)((uint)sj << 9)));
      wsum += ww;
      acc.x += ww * bf2f(u.x); acc.y += ww * bf2f(u.y);
      acc.z += ww * bf2f(u.z); acc.w += ww * bf2f(u.w);
    }
  }

  float inv = 1.0f / wsum;  // deg>=1 via self-loop
  float4 v = make_float4(acc.x * inv, acc.y * inv, acc.z * inv, acc.w * inv);

  if (LAYER == 1) {
    const float4 bv = *(const float4*)(bias + lane * 4);
    v.x = fmaxf(v.x + bv.x, 0.f);
    v.y = fmaxf(v.y + bv.y, 0.f);
    v.z = fmaxf(v.z + bv.z, 0.f);
    v.w = fmaxf(v.w + bv.w, 0.f);
    ushort4 h, l;
    h.x = f2bf(v.x); l.x = f2bf(v.x - bf2f(h.x));
    h.y = f2bf(v.y); l.y = f2bf(v.y - bf2f(h.y));
    h.z = f2bf(v.z); l.z = f2bf(v.z - bf2f(h.z));
    h.w = f2bf(v.w); l.w = f2bf(v.w - bf2f(h.w));
    const size_t o = (size_t)node * 256 + lane * 4;
    *(ushort4*)(out_h + o) = h;
    *(ushort4*)(out_l + o) = l;
  } else {
    // fused finale: head-mean + bias + relu + softmax(64)
    v.x += __shfl_xor(v.x, 16); v.y += __shfl_xor(v.y, 16);
    v.z += __shfl_xor(v.z, 16); v.w += __shfl_xor(v.w, 16);
    v.x += __shfl_xor(v.x, 32); v.y += __shfl_xor(v.y, 32);
    v.z += __shfl_xor(v.z, 32); v.w += __shfl_xor(v.w, 32);
    const int c4 = (lane & 15) * 4;
    const float4 bv = *(const float4*)(bias + c4);
    v.x = fmaxf(v.x * 0.25f + bv.x, 0.f);
    v.y = fmaxf(v.y * 0.25f + bv.y, 0.f);
    v.z = fmaxf(v.z * 0.25f + bv.z, 0.f);
    v.w = fmaxf(v.w * 0.25f + bv.w, 0.f);
    float mx = fmaxf(fmaxf(v.x, v.y), fmaxf(v.z, v.w));
    for (int off = 8; off >= 1; off >>= 1) mx = fmaxf(mx, __shfl_xor(mx, off));
    v.x = __expf(v.x - mx); v.y = __expf(v.y - mx);
    v.z = __expf(v.z - mx); v.w = __expf(v.w - mx);
    float sum = v.x + v.y + v.z + v.w;
    for (int off = 8; off >= 1; off >>= 1) sum += __shfl_xor(sum, off);
    float is = 1.0f / sum;
    v.x *= is; v.y *= is; v.z *= is; v.w *= is;
    if (lane < 16) *(float4*)(outp + (size_t)node * 64 + c4) = v;
  }
}

// ---------------------------------------------------------------------------

extern "C" void kernel_launch(void* const* d_in, const int* in_sizes, int n_in,
                              void* d_out, int out_size, void* d_ws, size_t ws_size,
                              hipStream_t stream) {
  const float* x   = (const float*)d_in[0];
  const int*   ei  = (const int*)d_in[1];
  const float* W1  = (const float*)d_in[2];
  const float* as1 = (const float*)d_in[3];
  const float* ad1 = (const float*)d_in[4];
  const float* b1  = (const float*)d_in[5];
  const float* W2  = (const float*)d_in[6];
  const float* as2 = (const float*)d_in[7];
  const float* ad2 = (const float*)d_in[8];
  const float* b2  = (const float*)d_in[9];
  float* out = (float*)d_out;

  const int N = in_sizes[0] / 128;
  const int E = in_sizes[1] / 2;
  const int* srcv = ei;
  const int* dstv = ei + E;

  // ---- workspace layout
  ushort* h1   = (ushort*)d_ws;                   // [N,256] bf16 (also h2)
  ushort* hb_h = h1 + (size_t)N * 256;            // [N,256] bf16
  ushort* hb_l = hb_h + (size_t)N * 256;          // [N,256] bf16
  ushort* w1th = hb_l + (size_t)N * 256;          // [256][128] x2
  ushort* w1tl = w1th + 256 * 128;
  ushort* w2th = w1tl + 256 * 128;                // [256][256] x2
  ushort* w2tl = w2th + 256 * 256;
  float*  zbuf = (float*)(w2tl + 256 * 256);      // a_s1,a_d1,a_s2,a_d2 [16N]
  float* a_s1 = zbuf;
  float* a_d1 = a_s1 + (size_t)N * 4;
  float* a_s2 = a_d1 + (size_t)N * 4;
  float* a_d2 = a_s2 + (size_t)N * 4;
  int* rowptr = (int*)(zbuf + (size_t)N * 16);    // [N+1] (+pad)
  int* cnt    = rowptr + (N + 4);                 // [N]      (memset region)
  int* bflag  = cnt + N;                          // [256]    (memset region)
  int* bsum   = bflag + 256;                      // [256]
  int* cursor = bsum + 256;                       // [N]
  int* colx   = cursor + N;                       // [E]

  const int nb = (N + 255) / 256;  // <=256 required by k_scan lookback
  const int eb = (E + 255) / 256;

  hipMemsetAsync(cnt, 0, ((size_t)N + 256) * 4, stream);  // cnt + bflag
  k_hist<<<eb, 256, 0, stream>>>(dstv, cnt, E);
  k_scan<<<nb, 256, 0, stream>>>(cnt, rowptr, cursor, bsum, bflag, N, E);
  k_scatter<<<eb, 256, 0, stream>>>(srcv, dstv, cursor, colx, E);
  k_prep_w<<<384, 256, 0, stream>>>(W1, W2, w1th, w1tl, w2th, w2tl);

  // XCD-aligned swizzled 1-D grid: 16 blocks per group of 8 row blocks
  const int nrb = (N + 127) / 128;
  const int gemm_blocks = ((nrb + 7) / 8) * 16;
  const int wb = (N + 3) / 4;  // one wave per node

  k_gemm_mfma<1><<<gemm_blocks, 256, 0, stream>>>(x, nullptr, w1th, w1tl,
                                                  h1, N, 128,
                                                  as1, ad1, a_s1, a_d1);
  k_aggr<1><<<wb, 256, 0, stream>>>(h1, rowptr, colx, a_s1, a_d1, b1,
                                    hb_h, hb_l, nullptr, N);
  k_gemm_mfma<0><<<gemm_blocks, 256, 0, stream>>>(hb_h, hb_l, w2th, w2tl,
                                                  h1, N, 256,
                                                  as2, ad2, a_s2, a_d2);
  k_aggr<2><<<wb, 256, 0, stream>>>(h1, rowptr, colx, a_s2, a_d2, b2,
                                    nullptr, nullptr, out, N);
}